// Round 1
// baseline (114.641 us; speedup 1.0000x reference)
//
#include <hip/hip_runtime.h>
#include <math.h>

#define N1 10242
#define N2 40962
#define N3 163842

constexpr float EPS_F = 1e-5f;
constexpr float SLOPE = 0.2f;
constexpr int TB = 256;
constexpr int STATS_BLOCKS = 64;

static inline int cdiv(int a, int b) { return (a + b - 1) / b; }

// ---------------- fc_age: (1,1)@(1,64) + b -> 64 ----------------
__global__ void k_fc_age(const float* __restrict__ age,
                         const float* __restrict__ w,
                         const float* __restrict__ b,
                         float* __restrict__ out) {
    int j = threadIdx.x;
    if (j < 64) out[j] = age[0] * w[j] + b[j];
}

// ---------------- fc: (64) @ fc_w.T + b -> 3*N1 ----------------
__global__ void k_fc_big(const float* __restrict__ x64,
                         const float* __restrict__ w,   // (3N1, 64) row-major
                         const float* __restrict__ b,
                         float* __restrict__ out, int n) {
    __shared__ float xs[64];
    if (threadIdx.x < 64) xs[threadIdx.x] = x64[threadIdx.x];
    __syncthreads();
    int i = blockIdx.x * blockDim.x + threadIdx.x;
    if (i >= n) return;
    const float4* wr = (const float4*)(w + (size_t)i * 64);
    float acc = 0.f;
#pragma unroll
    for (int q = 0; q < 16; ++q) {
        float4 v = wr[q];
        acc = fmaf(v.x, xs[q * 4 + 0], acc);
        acc = fmaf(v.y, xs[q * 4 + 1], acc);
        acc = fmaf(v.z, xs[q * 4 + 2], acc);
        acc = fmaf(v.w, xs[q * 4 + 3], acc);
    }
    out[i] = acc + b[i];
}

// ---------------- BN stats stage 1: per-block partial sums (double) ----------------
template <int C>
__global__ void k_stats1(const float* __restrict__ x, int n, double* __restrict__ part) {
    double s[C], q[C];
#pragma unroll
    for (int c = 0; c < C; ++c) { s[c] = 0.0; q[c] = 0.0; }
    int stride = gridDim.x * blockDim.x;
    for (int i = blockIdx.x * blockDim.x + threadIdx.x; i < n; i += stride) {
#pragma unroll
        for (int c = 0; c < C; ++c) {
            double v = (double)x[(size_t)i * C + c];
            s[c] += v;
            q[c] += v * v;
        }
    }
    __shared__ double sh[TB * 2 * C];
    int tid = threadIdx.x;
#pragma unroll
    for (int c = 0; c < C; ++c) {
        sh[tid * 2 * C + c] = s[c];
        sh[tid * 2 * C + C + c] = q[c];
    }
    __syncthreads();
    for (int off = TB / 2; off > 0; off >>= 1) {
        if (tid < off) {
#pragma unroll
            for (int k = 0; k < 2 * C; ++k) sh[tid * 2 * C + k] += sh[(tid + off) * 2 * C + k];
        }
        __syncthreads();
    }
    if (tid == 0) {
#pragma unroll
        for (int k = 0; k < 2 * C; ++k) part[(size_t)blockIdx.x * 2 * C + k] = sh[k];
    }
}

// ---------------- BN stats stage 2: finalize -> scale[C], shift[C] ----------------
template <int C>
__global__ void k_stats2(const double* __restrict__ part, int n,
                         const float* __restrict__ g, const float* __restrict__ bb,
                         float* __restrict__ ss) {
    __shared__ double tot[2 * C];
    int tid = threadIdx.x;
    if (tid < 2 * C) {
        double a = 0.0;
        for (int i = 0; i < STATS_BLOCKS; ++i) a += part[(size_t)i * 2 * C + tid];
        tot[tid] = a;
    }
    __syncthreads();
    if (tid < C) {
        double mean = tot[tid] / (double)n;
        double var = tot[C + tid] / (double)n - mean * mean;
        if (var < 0.0) var = 0.0;
        float rstd = (float)(1.0 / sqrt(var + (double)EPS_F));
        float sc = g[tid] * rstd;
        ss[tid] = sc;
        ss[C + tid] = bb[tid] - (float)mean * sc;
    }
}

// ---------------- upconv linear: bn+lrelu then (3 -> 21) per row ----------------
__global__ void k_up(const float* __restrict__ x, int R,
                     const float* __restrict__ ss,  // scale[3], shift[3]
                     const float* __restrict__ w,   // (21,3) row-major
                     const float* __restrict__ b,   // (21)
                     float* __restrict__ y) {       // (R,21)
    int r = blockIdx.x * blockDim.x + threadIdx.x;
    if (r >= R) return;
    float a0, a1, a2;
    {
        float v0 = fmaf(x[(size_t)r * 3 + 0], ss[0], ss[3]);
        float v1 = fmaf(x[(size_t)r * 3 + 1], ss[1], ss[4]);
        float v2 = fmaf(x[(size_t)r * 3 + 2], ss[2], ss[5]);
        a0 = v0 >= 0.f ? v0 : SLOPE * v0;
        a1 = v1 >= 0.f ? v1 : SLOPE * v1;
        a2 = v2 >= 0.f ? v2 : SLOPE * v2;
    }
    float* yo = y + (size_t)r * 21;
#pragma unroll
    for (int j = 0; j < 21; ++j) {
        yo[j] = fmaf(a0, w[j * 3 + 0], fmaf(a1, w[j * 3 + 1], fmaf(a2, w[j * 3 + 2], b[j])));
    }
}

// ---------------- scatter: centers + paired-edge means (channel-mixing reshape!) ----------------
__global__ void k_scatter(const float* __restrict__ y,   // (R*7, 3) flat
                          const int* __restrict__ top,   // (R)
                          const int* __restrict__ down,  // (2K) row indices into (R*7)
                          int R, int Nn,
                          float* __restrict__ out) {     // (Nn, 3)
    int i = blockIdx.x * blockDim.x + threadIdx.x;
    if (i >= Nn) return;
    if (i < R) {
        int t = top[i];
        const float* ys = y + (size_t)t * 3;
        out[(size_t)i * 3 + 0] = ys[0];
        out[(size_t)i * 3 + 1] = ys[1];
        out[(size_t)i * 3 + 2] = ys[2];
    } else {
        int k = i - R;
        int d0 = down[2 * k + 0];
        int d1 = down[2 * k + 1];
        const float* y0 = y + (size_t)d0 * 3;
        const float* y1 = y + (size_t)d1 * 3;
        // y[down].reshape(-1,3,2).mean(-1) with C=3 mixes channels across the row pair:
        out[(size_t)i * 3 + 0] = 0.5f * (y0[0] + y0[1]);
        out[(size_t)i * 3 + 1] = 0.5f * (y0[2] + y1[0]);
        out[(size_t)i * 3 + 2] = 0.5f * (y1[1] + y1[2]);
    }
}

// ---------------- one-ring conv: bn+lrelu on the fly, gather 7, matmul ----------------
template <int CIN, int COUT>
__global__ void k_conv(const float* __restrict__ x,      // (n, CIN) raw (pre-BN)
                       const int* __restrict__ neigh,    // (n*7)
                       const float* __restrict__ ss,     // scale[CIN], shift[CIN]
                       const float* __restrict__ w,      // (COUT, 7*CIN)
                       const float* __restrict__ b,      // (COUT)
                       float* __restrict__ out, int n) {
    __shared__ float wsm[COUT * 7 * CIN];
    __shared__ float bs[COUT];
    __shared__ float sss[2 * CIN];
    for (int t = threadIdx.x; t < COUT * 7 * CIN; t += blockDim.x) wsm[t] = w[t];
    if (threadIdx.x < COUT) bs[threadIdx.x] = b[threadIdx.x];
    if (threadIdx.x < 2 * CIN) sss[threadIdx.x] = ss[threadIdx.x];
    __syncthreads();
    int i = blockIdx.x * blockDim.x + threadIdx.x;
    if (i >= n) return;
    float acc[COUT];
#pragma unroll
    for (int o = 0; o < COUT; ++o) acc[o] = bs[o];
#pragma unroll
    for (int j = 0; j < 7; ++j) {
        int v = neigh[(size_t)i * 7 + j];
        const float* xr = x + (size_t)v * CIN;
#pragma unroll
        for (int c = 0; c < CIN; ++c) {
            float t = fmaf(xr[c], sss[c], sss[CIN + c]);
            t = t >= 0.f ? t : SLOPE * t;
#pragma unroll
            for (int o = 0; o < COUT; ++o) acc[o] = fmaf(t, wsm[o * 7 * CIN + j * CIN + c], acc[o]);
        }
    }
#pragma unroll
    for (int o = 0; o < COUT; ++o) out[(size_t)i * COUT + o] = acc[o];
}

extern "C" void kernel_launch(void* const* d_in, const int* in_sizes, int n_in,
                              void* d_out, int out_size, void* d_ws, size_t ws_size,
                              hipStream_t stream) {
    const float* age      = (const float*)d_in[0];
    const float* fc_age_w = (const float*)d_in[1];
    const float* fc_age_b = (const float*)d_in[2];
    const float* fc_w     = (const float*)d_in[3];
    const float* fc_b     = (const float*)d_in[4];
    const float* bn_up0_g = (const float*)d_in[5];
    const float* bn_up0_b = (const float*)d_in[6];
    const float* up0_w    = (const float*)d_in[7];
    const float* up0_b    = (const float*)d_in[8];
    const float* bn_up1_g = (const float*)d_in[9];
    const float* bn_up1_b = (const float*)d_in[10];
    const float* up1_w    = (const float*)d_in[11];
    const float* up1_b    = (const float*)d_in[12];
    const float* bn0_g    = (const float*)d_in[13];
    const float* bn0_b    = (const float*)d_in[14];
    const float* conv0_w  = (const float*)d_in[15];
    const float* conv0_b  = (const float*)d_in[16];
    const float* bn1_g    = (const float*)d_in[17];
    const float* bn1_b    = (const float*)d_in[18];
    const float* conv1_w  = (const float*)d_in[19];
    const float* conv1_b  = (const float*)d_in[20];
    const float* bn2_g    = (const float*)d_in[21];
    const float* bn2_b    = (const float*)d_in[22];
    const float* conv2_w  = (const float*)d_in[23];
    const float* conv2_b  = (const float*)d_in[24];
    const int* up_top0    = (const int*)d_in[25];
    const int* up_down0   = (const int*)d_in[26];
    const int* up_top1    = (const int*)d_in[27];
    const int* up_down1   = (const int*)d_in[28];
    const int* neigh      = (const int*)d_in[29];

    float* ws   = (float*)d_ws;
    float* bufA = ws;                          // N3*8 floats
    float* bufB = ws + (size_t)N3 * 8;         // N3*8 floats
    float* x64  = ws + (size_t)2 * N3 * 8;     // 64
    float* ss0  = x64 + 64;                    // 6 (pad to 8)
    float* ss1  = ss0 + 8;                     // 6
    float* ss2  = ss1 + 8;                     // 6
    float* ss3  = ss2 + 8;                     // 16
    float* ss4  = ss3 + 16;                    // 16
    double* part = (double*)(ws + (size_t)2 * N3 * 8 + 128);  // 64*16 doubles

    // 1) age -> 64
    k_fc_age<<<1, 64, 0, stream>>>(age, fc_age_w, fc_age_b, x64);
    // 2) 64 -> (N1,3) into bufA
    k_fc_big<<<cdiv(3 * N1, TB), TB, 0, stream>>>(x64, fc_w, fc_b, bufA, 3 * N1);

    // --- up block 0: N1 -> N2 ---
    k_stats1<3><<<STATS_BLOCKS, TB, 0, stream>>>(bufA, N1, part);
    k_stats2<3><<<1, 64, 0, stream>>>(part, N1, bn_up0_g, bn_up0_b, ss0);
    k_up<<<cdiv(N1, TB), TB, 0, stream>>>(bufA, N1, ss0, up0_w, up0_b, bufB);
    k_scatter<<<cdiv(N2, TB), TB, 0, stream>>>(bufB, up_top0, up_down0, N1, N2, bufA);

    // --- up block 1: N2 -> N3 ---
    k_stats1<3><<<STATS_BLOCKS, TB, 0, stream>>>(bufA, N2, part);
    k_stats2<3><<<1, 64, 0, stream>>>(part, N2, bn_up1_g, bn_up1_b, ss1);
    k_up<<<cdiv(N2, TB), TB, 0, stream>>>(bufA, N2, ss1, up1_w, up1_b, bufB);
    k_scatter<<<cdiv(N3, TB), TB, 0, stream>>>(bufB, up_top1, up_down1, N2, N3, bufA);

    // --- conv0: (N3,3) -> (N3,8) ---
    k_stats1<3><<<STATS_BLOCKS, TB, 0, stream>>>(bufA, N3, part);
    k_stats2<3><<<1, 64, 0, stream>>>(part, N3, bn0_g, bn0_b, ss2);
    k_conv<3, 8><<<cdiv(N3, TB), TB, 0, stream>>>(bufA, neigh, ss2, conv0_w, conv0_b, bufB, N3);

    // --- conv1: (N3,8) -> (N3,8) ---
    k_stats1<8><<<STATS_BLOCKS, TB, 0, stream>>>(bufB, N3, part);
    k_stats2<8><<<1, 64, 0, stream>>>(part, N3, bn1_g, bn1_b, ss3);
    k_conv<8, 8><<<cdiv(N3, TB), TB, 0, stream>>>(bufB, neigh, ss3, conv1_w, conv1_b, bufA, N3);

    // --- conv2: (N3,8) -> (N3,2) ---
    k_stats1<8><<<STATS_BLOCKS, TB, 0, stream>>>(bufA, N3, part);
    k_stats2<8><<<1, 64, 0, stream>>>(part, N3, bn2_g, bn2_b, ss4);
    k_conv<8, 2><<<cdiv(N3, TB), TB, 0, stream>>>(bufA, neigh, ss4, conv2_w, conv2_b, (float*)d_out, N3);
}

// Round 2
// 109.564 us; speedup vs baseline: 1.0463x; 1.0463x over previous
//
#include <hip/hip_runtime.h>
#include <math.h>

#define N1 10242
#define N2 40962
#define N3 163842

constexpr float SLOPE = 0.2f;
constexpr int TB = 256;

static inline int cdiv(int a, int b) { return (a + b - 1) / b; }

// ---- finalize BN stats from per-block partials (every block does this redundantly) ----
// part: nb x (2C) doubles [sum_0..C-1, sumsq_0..C-1]; writes ss[2C] floats in shared:
// ss[c] = scale_c, ss[C+c] = shift_c
template <int C>
__device__ void finalize_ss(const double* __restrict__ part, int nb, int n,
                            const float* __restrict__ g, const float* __restrict__ bb,
                            float* ss) {
    constexpr int K = 2 * C;
    constexpr int G = TB / K;
    __shared__ double red[TB];
    __shared__ double tot[K];
    int tid = threadIdx.x;
    double s = 0.0;
    if (tid < G * K) {
        int k = tid % K, i0 = tid / K;
        for (int i = i0; i < nb; i += G) s += part[(size_t)i * K + k];
    }
    red[tid] = s;
    __syncthreads();
    if (tid < K) {
        double t = 0.0;
        for (int j = 0; j < G; ++j) t += red[j * K + tid];
        tot[tid] = t;
    }
    __syncthreads();
    if (tid < C) {
        double mean = tot[tid] / (double)n;
        double var = tot[C + tid] / (double)n - mean * mean;
        if (var < 0.0) var = 0.0;
        float rstd = (float)(1.0 / sqrt(var + 1e-5));
        float sc = g[tid] * rstd;
        ss[tid] = sc;
        ss[C + tid] = bb[tid] - (float)mean * sc;
    }
    __syncthreads();
}

// ---- block tree-reduce of K doubles per thread, write one partial row ----
template <int K>
__device__ void block_reduce_part(double* sh, double* __restrict__ part_out, int bid) {
    int tid = threadIdx.x;
    __syncthreads();
    for (int off = TB / 2; off > 0; off >>= 1) {
        if (tid < off) {
#pragma unroll
            for (int k = 0; k < K; ++k) sh[tid * K + k] += sh[(tid + off) * K + k];
        }
        __syncthreads();
    }
    if (tid < K) part_out[(size_t)bid * K + tid] = sh[tid];
}

// ================= Kernel A: fc_age + fc + stats(3) =================
__global__ void k_fc_stats(const float* __restrict__ age,
                           const float* __restrict__ aw, const float* __restrict__ ab,
                           const float* __restrict__ w, const float* __restrict__ b,
                           float* __restrict__ out, double* __restrict__ part) {
    __shared__ float xs[64];
    __shared__ double sh[TB * 6];
    int tid = threadIdx.x;
    if (tid < 64) xs[tid] = age[0] * aw[tid] + ab[tid];
    __syncthreads();
    int i = blockIdx.x * TB + tid;
    float val = 0.f;
    bool valid = i < 3 * N1;
    if (valid) {
        const float4* wr = (const float4*)(w + (size_t)i * 64);
        float acc = 0.f;
#pragma unroll
        for (int q = 0; q < 16; ++q) {
            float4 v = wr[q];
            acc = fmaf(v.x, xs[4 * q + 0], acc);
            acc = fmaf(v.y, xs[4 * q + 1], acc);
            acc = fmaf(v.z, xs[4 * q + 2], acc);
            acc = fmaf(v.w, xs[4 * q + 3], acc);
        }
        val = acc + b[i];
        out[i] = val;
    }
#pragma unroll
    for (int k = 0; k < 6; ++k) sh[tid * 6 + k] = 0.0;
    if (valid) {
        int c = i % 3;
        sh[tid * 6 + c] = (double)val;
        sh[tid * 6 + 3 + c] = (double)val * (double)val;
    }
    block_reduce_part<6>(sh, part, blockIdx.x);
}

// ================= Kernel B: BN+LReLU + up-linear + scatter + stats(3) =================
__device__ inline float yv(const float* a, const float* wsm, const float* bsm, int col) {
    return fmaf(a[0], wsm[col * 3 + 0],
           fmaf(a[1], wsm[col * 3 + 1],
           fmaf(a[2], wsm[col * 3 + 2], bsm[col])));
}

__global__ void k_up_fused(const float* __restrict__ x, int R, int Nn,
                           const double* __restrict__ part, int nb, int nprev,
                           const float* __restrict__ g, const float* __restrict__ bb,
                           const float* __restrict__ w, const float* __restrict__ b,
                           const int* __restrict__ top, const int* __restrict__ down,
                           float* __restrict__ out, double* __restrict__ opart) {
    __shared__ float ss[6];
    __shared__ float wsm[63], bsm[21];
    __shared__ double sh[TB * 6];
    finalize_ss<3>(part, nb, nprev, g, bb, ss);
    int tid = threadIdx.x;
    if (tid < 63) wsm[tid] = w[tid];
    if (tid < 21) bsm[tid] = b[tid];
    __syncthreads();
    int i = blockIdx.x * TB + tid;
    float o0 = 0.f, o1 = 0.f, o2 = 0.f;
    bool valid = i < Nn;
    if (valid) {
        if (i < R) {
            int t = top[i];
            int r = t / 7, jg = t % 7;
            float a[3];
#pragma unroll
            for (int c = 0; c < 3; ++c) {
                float v = fmaf(x[(size_t)r * 3 + c], ss[c], ss[3 + c]);
                a[c] = v >= 0.f ? v : SLOPE * v;
            }
            o0 = yv(a, wsm, bsm, jg * 3 + 0);
            o1 = yv(a, wsm, bsm, jg * 3 + 1);
            o2 = yv(a, wsm, bsm, jg * 3 + 2);
        } else {
            int k2 = i - R;
            int d0 = down[2 * k2 + 0];
            int d1 = down[2 * k2 + 1];
            int r0 = d0 / 7, j0 = d0 % 7;
            int r1 = d1 / 7, j1 = d1 % 7;
            float a0[3], a1[3];
#pragma unroll
            for (int c = 0; c < 3; ++c) {
                float v = fmaf(x[(size_t)r0 * 3 + c], ss[c], ss[3 + c]);
                a0[c] = v >= 0.f ? v : SLOPE * v;
                float u = fmaf(x[(size_t)r1 * 3 + c], ss[c], ss[3 + c]);
                a1[c] = u >= 0.f ? u : SLOPE * u;
            }
            float y00 = yv(a0, wsm, bsm, j0 * 3 + 0);
            float y01 = yv(a0, wsm, bsm, j0 * 3 + 1);
            float y02 = yv(a0, wsm, bsm, j0 * 3 + 2);
            float y10 = yv(a1, wsm, bsm, j1 * 3 + 0);
            float y11 = yv(a1, wsm, bsm, j1 * 3 + 1);
            float y12 = yv(a1, wsm, bsm, j1 * 3 + 2);
            // y[down].reshape(-1,3,2).mean(-1): channel-mixing across the row pair
            o0 = 0.5f * (y00 + y01);
            o1 = 0.5f * (y02 + y10);
            o2 = 0.5f * (y11 + y12);
        }
        out[(size_t)i * 3 + 0] = o0;
        out[(size_t)i * 3 + 1] = o1;
        out[(size_t)i * 3 + 2] = o2;
    }
#pragma unroll
    for (int k = 0; k < 6; ++k) sh[tid * 6 + k] = 0.0;
    if (valid) {
        sh[tid * 6 + 0] = (double)o0;
        sh[tid * 6 + 1] = (double)o1;
        sh[tid * 6 + 2] = (double)o2;
        sh[tid * 6 + 3] = (double)o0 * o0;
        sh[tid * 6 + 4] = (double)o1 * o1;
        sh[tid * 6 + 5] = (double)o2 * o2;
    }
    block_reduce_part<6>(sh, opart, blockIdx.x);
}

// ================= Kernel C: BN+LReLU + one-ring conv (+ stats COUT) =================
template <int CIN, int COUT, bool STATS>
__global__ void k_conv_fused(const float* __restrict__ x, const int* __restrict__ neigh,
                             const double* __restrict__ part, int nb, int nprev,
                             const float* __restrict__ g, const float* __restrict__ bb,
                             const float* __restrict__ w, const float* __restrict__ b,
                             float* __restrict__ out, double* __restrict__ opart, int n) {
    __shared__ float ss[2 * CIN];
    __shared__ float wsm[COUT * 7 * CIN];
    __shared__ float bsm[COUT];
    finalize_ss<CIN>(part, nb, nprev, g, bb, ss);
    int tid = threadIdx.x;
    for (int t = tid; t < COUT * 7 * CIN; t += TB) wsm[t] = w[t];
    if (tid < COUT) bsm[tid] = b[tid];
    __syncthreads();
    int i = blockIdx.x * TB + tid;
    float acc[COUT];
#pragma unroll
    for (int o = 0; o < COUT; ++o) acc[o] = 0.f;
    bool valid = i < n;
    if (valid) {
#pragma unroll
        for (int o = 0; o < COUT; ++o) acc[o] = bsm[o];
#pragma unroll
        for (int j = 0; j < 7; ++j) {
            int v = neigh[(size_t)i * 7 + j];
            float xv[CIN];
            if constexpr (CIN == 8) {
                const float4* xr = (const float4*)(x + (size_t)v * 8);
                float4 p = xr[0], q = xr[1];
                xv[0] = p.x; xv[1] = p.y; xv[2] = p.z; xv[3] = p.w;
                xv[4] = q.x; xv[5] = q.y; xv[6] = q.z; xv[7] = q.w;
            } else {
#pragma unroll
                for (int c = 0; c < CIN; ++c) xv[c] = x[(size_t)v * CIN + c];
            }
#pragma unroll
            for (int c = 0; c < CIN; ++c) {
                float t = fmaf(xv[c], ss[c], ss[CIN + c]);
                t = t >= 0.f ? t : SLOPE * t;
#pragma unroll
                for (int o = 0; o < COUT; ++o)
                    acc[o] = fmaf(t, wsm[o * 7 * CIN + j * CIN + c], acc[o]);
            }
        }
        if constexpr (COUT == 8) {
            float4* op = (float4*)(out + (size_t)i * 8);
            op[0] = make_float4(acc[0], acc[1], acc[2], acc[3]);
            op[1] = make_float4(acc[4], acc[5], acc[6], acc[7]);
        } else {
#pragma unroll
            for (int o = 0; o < COUT; ++o) out[(size_t)i * COUT + o] = acc[o];
        }
    }
    if constexpr (STATS) {
        __shared__ double sh[TB * 2 * COUT];
#pragma unroll
        for (int o = 0; o < COUT; ++o) {
            double v = valid ? (double)acc[o] : 0.0;
            sh[tid * 2 * COUT + o] = v;
            sh[tid * 2 * COUT + COUT + o] = v * v;
        }
        block_reduce_part<2 * COUT>(sh, opart, blockIdx.x);
    }
}

extern "C" void kernel_launch(void* const* d_in, const int* in_sizes, int n_in,
                              void* d_out, int out_size, void* d_ws, size_t ws_size,
                              hipStream_t stream) {
    const float* age      = (const float*)d_in[0];
    const float* fc_age_w = (const float*)d_in[1];
    const float* fc_age_b = (const float*)d_in[2];
    const float* fc_w     = (const float*)d_in[3];
    const float* fc_b     = (const float*)d_in[4];
    const float* bn_up0_g = (const float*)d_in[5];
    const float* bn_up0_b = (const float*)d_in[6];
    const float* up0_w    = (const float*)d_in[7];
    const float* up0_b    = (const float*)d_in[8];
    const float* bn_up1_g = (const float*)d_in[9];
    const float* bn_up1_b = (const float*)d_in[10];
    const float* up1_w    = (const float*)d_in[11];
    const float* up1_b    = (const float*)d_in[12];
    const float* bn0_g    = (const float*)d_in[13];
    const float* bn0_b    = (const float*)d_in[14];
    const float* conv0_w  = (const float*)d_in[15];
    const float* conv0_b  = (const float*)d_in[16];
    const float* bn1_g    = (const float*)d_in[17];
    const float* bn1_b    = (const float*)d_in[18];
    const float* conv1_w  = (const float*)d_in[19];
    const float* conv1_b  = (const float*)d_in[20];
    const float* bn2_g    = (const float*)d_in[21];
    const float* bn2_b    = (const float*)d_in[22];
    const float* conv2_w  = (const float*)d_in[23];
    const float* conv2_b  = (const float*)d_in[24];
    const int* up_top0    = (const int*)d_in[25];
    const int* up_down0   = (const int*)d_in[26];
    const int* up_top1    = (const int*)d_in[27];
    const int* up_down1   = (const int*)d_in[28];
    const int* neigh      = (const int*)d_in[29];

    float* ws   = (float*)d_ws;
    float* bufA = ws;                      // N3*8 floats
    float* bufB = ws + (size_t)N3 * 8;     // N3*8 floats
    // doubles after the two float buffers (offset 2*N3*8*4 bytes, 8B-aligned)
    double* dbase  = (double*)((char*)d_ws + (size_t)2 * N3 * 8 * 4);
    double* partA  = dbase;                 // 121*6
    double* partB0 = partA + 1024;          // 161*6
    double* partB1 = partB0 + 1024;         // 641*6
    double* partC0 = partB1 + 4096;         // 641*16
    double* partC1 = partC0 + 10752;        // 641*16

    const int nbA  = cdiv(3 * N1, TB);  // 121
    const int nbB0 = cdiv(N2, TB);      // 161
    const int nbB1 = cdiv(N3, TB);      // 641
    const int nbC  = cdiv(N3, TB);      // 641

    // 1) fc_age + fc -> bufA (N1,3), stats partials
    k_fc_stats<<<nbA, TB, 0, stream>>>(age, fc_age_w, fc_age_b, fc_w, fc_b, bufA, partA);

    // 2) up0: N1 -> N2 (bufA -> bufB), finalize partA, emit partB0
    k_up_fused<<<nbB0, TB, 0, stream>>>(bufA, N1, N2, partA, nbA, N1,
                                        bn_up0_g, bn_up0_b, up0_w, up0_b,
                                        up_top0, up_down0, bufB, partB0);

    // 3) up1: N2 -> N3 (bufB -> bufA), finalize partB0, emit partB1
    k_up_fused<<<nbB1, TB, 0, stream>>>(bufB, N2, N3, partB0, nbB0, N2,
                                        bn_up1_g, bn_up1_b, up1_w, up1_b,
                                        up_top1, up_down1, bufA, partB1);

    // 4) conv0: (N3,3) -> (N3,8) (bufA -> bufB), finalize partB1, emit partC0
    k_conv_fused<3, 8, true><<<nbC, TB, 0, stream>>>(bufA, neigh, partB1, nbB1, N3,
                                                     bn0_g, bn0_b, conv0_w, conv0_b,
                                                     bufB, partC0, N3);

    // 5) conv1: (N3,8) -> (N3,8) (bufB -> bufA), finalize partC0, emit partC1
    k_conv_fused<8, 8, true><<<nbC, TB, 0, stream>>>(bufB, neigh, partC0, nbC, N3,
                                                     bn1_g, bn1_b, conv1_w, conv1_b,
                                                     bufA, partC1, N3);

    // 6) conv2: (N3,8) -> (N3,2) (bufA -> d_out), finalize partC1
    k_conv_fused<8, 2, false><<<nbC, TB, 0, stream>>>(bufA, neigh, partC1, nbC, N3,
                                                      bn2_g, bn2_b, conv2_w, conv2_b,
                                                      (float*)d_out, nullptr, N3);
}

// Round 3
// 104.590 us; speedup vs baseline: 1.0961x; 1.0476x over previous
//
#include <hip/hip_runtime.h>
#include <math.h>

#define N1 10242
#define N2 40962
#define N3 163842

constexpr float SLOPE = 0.2f;
constexpr int TB = 256;

static inline int cdiv(int a, int b) { return (a + b - 1) / b; }

// ---- finalize BN stats from per-block partials (every block does this redundantly) ----
// part: nb x (2C) doubles [sum_0..C-1, sumsq_0..C-1]; writes ss[2C] floats in shared:
// ss[c] = scale_c, ss[C+c] = shift_c
template <int C>
__device__ void finalize_ss(const double* __restrict__ part, int nb, int n,
                            const float* __restrict__ g, const float* __restrict__ bb,
                            float* ss) {
    constexpr int K = 2 * C;
    constexpr int G = TB / K;
    __shared__ double red[TB];
    __shared__ double tot[K];
    int tid = threadIdx.x;
    double s = 0.0;
    if (tid < G * K) {
        int k = tid % K, i0 = tid / K;
        for (int i = i0; i < nb; i += G) s += part[(size_t)i * K + k];
    }
    red[tid] = s;
    __syncthreads();
    if (tid < K) {
        double t = 0.0;
        for (int j = 0; j < G; ++j) t += red[j * K + tid];
        tot[tid] = t;
    }
    __syncthreads();
    if (tid < C) {
        double mean = tot[tid] / (double)n;
        double var = tot[C + tid] / (double)n - mean * mean;
        if (var < 0.0) var = 0.0;
        float rstd = (float)(1.0 / sqrt(var + 1e-5));
        float sc = g[tid] * rstd;
        ss[tid] = sc;
        ss[C + tid] = bb[tid] - (float)mean * sc;
    }
    __syncthreads();
}

// ---- block reduce of K doubles per thread via wave butterfly + tiny LDS combine ----
// v[k] are per-thread contributions. Writes part_out[bid*K + k]. Conflict-free:
// intra-wave via __shfl_xor (register permute network), cross-wave via 4xK LDS rows.
template <int K>
__device__ void block_reduce_part(double* v, double* __restrict__ part_out, int bid) {
    __shared__ double shred[4 * K];
#pragma unroll
    for (int m = 1; m < 64; m <<= 1) {
#pragma unroll
        for (int k = 0; k < K; ++k) v[k] += __shfl_xor(v[k], m, 64);
    }
    int lane = threadIdx.x & 63, wid = threadIdx.x >> 6;
    if (lane < K) shred[wid * K + lane] = v[lane];  // v[k] uniform across wave; lane k writes k
    __syncthreads();
    int tid = threadIdx.x;
    if (tid < K) {
        double t = shred[tid] + shred[K + tid] + shred[2 * K + tid] + shred[3 * K + tid];
        part_out[(size_t)bid * K + tid] = t;
    }
}

// ================= Kernel A: fc_age + fc + stats(3) =================
__global__ void k_fc_stats(const float* __restrict__ age,
                           const float* __restrict__ aw, const float* __restrict__ ab,
                           const float* __restrict__ w, const float* __restrict__ b,
                           float* __restrict__ out, double* __restrict__ part) {
    __shared__ float xs[64];
    int tid = threadIdx.x;
    if (tid < 64) xs[tid] = age[0] * aw[tid] + ab[tid];
    __syncthreads();
    int i = blockIdx.x * TB + tid;
    float val = 0.f;
    bool valid = i < 3 * N1;
    if (valid) {
        const float4* wr = (const float4*)(w + (size_t)i * 64);
        float acc = 0.f;
#pragma unroll
        for (int q = 0; q < 16; ++q) {
            float4 v = wr[q];
            acc = fmaf(v.x, xs[4 * q + 0], acc);
            acc = fmaf(v.y, xs[4 * q + 1], acc);
            acc = fmaf(v.z, xs[4 * q + 2], acc);
            acc = fmaf(v.w, xs[4 * q + 3], acc);
        }
        val = acc + b[i];
        out[i] = val;
    }
    double v[6];
#pragma unroll
    for (int k = 0; k < 6; ++k) v[k] = 0.0;
    if (valid) {
        int c = i % 3;
        v[c] = (double)val;
        v[3 + c] = (double)val * (double)val;
    }
    block_reduce_part<6>(v, part, blockIdx.x);
}

// ================= Kernel B: BN+LReLU + up-linear + scatter + stats(3) =================
__device__ inline float yv(const float* a, const float* wsm, const float* bsm, int col) {
    return fmaf(a[0], wsm[col * 3 + 0],
           fmaf(a[1], wsm[col * 3 + 1],
           fmaf(a[2], wsm[col * 3 + 2], bsm[col])));
}

__global__ void k_up_fused(const float* __restrict__ x, int R, int Nn,
                           const double* __restrict__ part, int nb, int nprev,
                           const float* __restrict__ g, const float* __restrict__ bb,
                           const float* __restrict__ w, const float* __restrict__ b,
                           const int* __restrict__ top, const int* __restrict__ down,
                           float* __restrict__ out, double* __restrict__ opart) {
    __shared__ float ss[6];
    __shared__ float wsm[63], bsm[21];
    finalize_ss<3>(part, nb, nprev, g, bb, ss);
    int tid = threadIdx.x;
    if (tid < 63) wsm[tid] = w[tid];
    if (tid < 21) bsm[tid] = b[tid];
    __syncthreads();
    int i = blockIdx.x * TB + tid;
    float o0 = 0.f, o1 = 0.f, o2 = 0.f;
    bool valid = i < Nn;
    if (valid) {
        if (i < R) {
            int t = top[i];
            int r = t / 7, jg = t % 7;
            float a[3];
#pragma unroll
            for (int c = 0; c < 3; ++c) {
                float v = fmaf(x[(size_t)r * 3 + c], ss[c], ss[3 + c]);
                a[c] = v >= 0.f ? v : SLOPE * v;
            }
            o0 = yv(a, wsm, bsm, jg * 3 + 0);
            o1 = yv(a, wsm, bsm, jg * 3 + 1);
            o2 = yv(a, wsm, bsm, jg * 3 + 2);
        } else {
            int k2 = i - R;
            int d0 = down[2 * k2 + 0];
            int d1 = down[2 * k2 + 1];
            int r0 = d0 / 7, j0 = d0 % 7;
            int r1 = d1 / 7, j1 = d1 % 7;
            float a0[3], a1[3];
#pragma unroll
            for (int c = 0; c < 3; ++c) {
                float v = fmaf(x[(size_t)r0 * 3 + c], ss[c], ss[3 + c]);
                a0[c] = v >= 0.f ? v : SLOPE * v;
                float u = fmaf(x[(size_t)r1 * 3 + c], ss[c], ss[3 + c]);
                a1[c] = u >= 0.f ? u : SLOPE * u;
            }
            float y00 = yv(a0, wsm, bsm, j0 * 3 + 0);
            float y01 = yv(a0, wsm, bsm, j0 * 3 + 1);
            float y02 = yv(a0, wsm, bsm, j0 * 3 + 2);
            float y10 = yv(a1, wsm, bsm, j1 * 3 + 0);
            float y11 = yv(a1, wsm, bsm, j1 * 3 + 1);
            float y12 = yv(a1, wsm, bsm, j1 * 3 + 2);
            // y[down].reshape(-1,3,2).mean(-1): channel-mixing across the row pair
            o0 = 0.5f * (y00 + y01);
            o1 = 0.5f * (y02 + y10);
            o2 = 0.5f * (y11 + y12);
        }
        out[(size_t)i * 3 + 0] = o0;
        out[(size_t)i * 3 + 1] = o1;
        out[(size_t)i * 3 + 2] = o2;
    }
    double v[6];
#pragma unroll
    for (int k = 0; k < 6; ++k) v[k] = 0.0;
    if (valid) {
        v[0] = (double)o0; v[1] = (double)o1; v[2] = (double)o2;
        v[3] = (double)o0 * o0; v[4] = (double)o1 * o1; v[5] = (double)o2 * o2;
    }
    block_reduce_part<6>(v, opart, blockIdx.x);
}

// ================= Kernel C: BN+LReLU + one-ring conv (+ stats COUT) =================
template <int CIN, int COUT, bool STATS>
__global__ void k_conv_fused(const float* __restrict__ x, const int* __restrict__ neigh,
                             const double* __restrict__ part, int nb, int nprev,
                             const float* __restrict__ g, const float* __restrict__ bb,
                             const float* __restrict__ w, const float* __restrict__ b,
                             float* __restrict__ out, double* __restrict__ opart, int n) {
    __shared__ float ss[2 * CIN];
    __shared__ float wsm[COUT * 7 * CIN];
    __shared__ float bsm[COUT];
    finalize_ss<CIN>(part, nb, nprev, g, bb, ss);
    int tid = threadIdx.x;
    for (int t = tid; t < COUT * 7 * CIN; t += TB) wsm[t] = w[t];
    if (tid < COUT) bsm[tid] = b[tid];
    __syncthreads();
    int i = blockIdx.x * TB + tid;
    float acc[COUT];
#pragma unroll
    for (int o = 0; o < COUT; ++o) acc[o] = 0.f;
    bool valid = i < n;
    if (valid) {
#pragma unroll
        for (int o = 0; o < COUT; ++o) acc[o] = bsm[o];
#pragma unroll
        for (int j = 0; j < 7; ++j) {
            int v = neigh[(size_t)i * 7 + j];
            float xv[CIN];
            if constexpr (CIN == 8) {
                const float4* xr = (const float4*)(x + (size_t)v * 8);
                float4 p = xr[0], q = xr[1];
                xv[0] = p.x; xv[1] = p.y; xv[2] = p.z; xv[3] = p.w;
                xv[4] = q.x; xv[5] = q.y; xv[6] = q.z; xv[7] = q.w;
            } else {
#pragma unroll
                for (int c = 0; c < CIN; ++c) xv[c] = x[(size_t)v * CIN + c];
            }
#pragma unroll
            for (int c = 0; c < CIN; ++c) {
                float t = fmaf(xv[c], ss[c], ss[CIN + c]);
                t = t >= 0.f ? t : SLOPE * t;
#pragma unroll
                for (int o = 0; o < COUT; ++o)
                    acc[o] = fmaf(t, wsm[o * 7 * CIN + j * CIN + c], acc[o]);
            }
        }
        if constexpr (COUT == 8) {
            float4* op = (float4*)(out + (size_t)i * 8);
            op[0] = make_float4(acc[0], acc[1], acc[2], acc[3]);
            op[1] = make_float4(acc[4], acc[5], acc[6], acc[7]);
        } else {
#pragma unroll
            for (int o = 0; o < COUT; ++o) out[(size_t)i * COUT + o] = acc[o];
        }
    }
    if constexpr (STATS) {
        double v[2 * COUT];
#pragma unroll
        for (int o = 0; o < COUT; ++o) {
            double t = valid ? (double)acc[o] : 0.0;
            v[o] = t;
            v[COUT + o] = t * t;
        }
        block_reduce_part<2 * COUT>(v, opart, blockIdx.x);
    }
}

extern "C" void kernel_launch(void* const* d_in, const int* in_sizes, int n_in,
                              void* d_out, int out_size, void* d_ws, size_t ws_size,
                              hipStream_t stream) {
    const float* age      = (const float*)d_in[0];
    const float* fc_age_w = (const float*)d_in[1];
    const float* fc_age_b = (const float*)d_in[2];
    const float* fc_w     = (const float*)d_in[3];
    const float* fc_b     = (const float*)d_in[4];
    const float* bn_up0_g = (const float*)d_in[5];
    const float* bn_up0_b = (const float*)d_in[6];
    const float* up0_w    = (const float*)d_in[7];
    const float* up0_b    = (const float*)d_in[8];
    const float* bn_up1_g = (const float*)d_in[9];
    const float* bn_up1_b = (const float*)d_in[10];
    const float* up1_w    = (const float*)d_in[11];
    const float* up1_b    = (const float*)d_in[12];
    const float* bn0_g    = (const float*)d_in[13];
    const float* bn0_b    = (const float*)d_in[14];
    const float* conv0_w  = (const float*)d_in[15];
    const float* conv0_b  = (const float*)d_in[16];
    const float* bn1_g    = (const float*)d_in[17];
    const float* bn1_b    = (const float*)d_in[18];
    const float* conv1_w  = (const float*)d_in[19];
    const float* conv1_b  = (const float*)d_in[20];
    const float* bn2_g    = (const float*)d_in[21];
    const float* bn2_b    = (const float*)d_in[22];
    const float* conv2_w  = (const float*)d_in[23];
    const float* conv2_b  = (const float*)d_in[24];
    const int* up_top0    = (const int*)d_in[25];
    const int* up_down0   = (const int*)d_in[26];
    const int* up_top1    = (const int*)d_in[27];
    const int* up_down1   = (const int*)d_in[28];
    const int* neigh      = (const int*)d_in[29];

    float* ws   = (float*)d_ws;
    float* bufA = ws;                      // N3*8 floats
    float* bufB = ws + (size_t)N3 * 8;     // N3*8 floats
    // doubles after the two float buffers (offset 2*N3*8*4 bytes, 8B-aligned)
    double* dbase  = (double*)((char*)d_ws + (size_t)2 * N3 * 8 * 4);
    double* partA  = dbase;                 // 121*6
    double* partB0 = partA + 1024;          // 161*6
    double* partB1 = partB0 + 1024;         // 641*6
    double* partC0 = partB1 + 4096;         // 641*16
    double* partC1 = partC0 + 10752;        // 641*16

    const int nbA  = cdiv(3 * N1, TB);  // 121
    const int nbB0 = cdiv(N2, TB);      // 161
    const int nbB1 = cdiv(N3, TB);      // 641
    const int nbC  = cdiv(N3, TB);      // 641

    // 1) fc_age + fc -> bufA (N1,3), stats partials
    k_fc_stats<<<nbA, TB, 0, stream>>>(age, fc_age_w, fc_age_b, fc_w, fc_b, bufA, partA);

    // 2) up0: N1 -> N2 (bufA -> bufB), finalize partA, emit partB0
    k_up_fused<<<nbB0, TB, 0, stream>>>(bufA, N1, N2, partA, nbA, N1,
                                        bn_up0_g, bn_up0_b, up0_w, up0_b,
                                        up_top0, up_down0, bufB, partB0);

    // 3) up1: N2 -> N3 (bufB -> bufA), finalize partB0, emit partB1
    k_up_fused<<<nbB1, TB, 0, stream>>>(bufB, N2, N3, partB0, nbB0, N2,
                                        bn_up1_g, bn_up1_b, up1_w, up1_b,
                                        up_top1, up_down1, bufA, partB1);

    // 4) conv0: (N3,3) -> (N3,8) (bufA -> bufB), finalize partB1, emit partC0
    k_conv_fused<3, 8, true><<<nbC, TB, 0, stream>>>(bufA, neigh, partB1, nbB1, N3,
                                                     bn0_g, bn0_b, conv0_w, conv0_b,
                                                     bufB, partC0, N3);

    // 5) conv1: (N3,8) -> (N3,8) (bufB -> bufA), finalize partC0, emit partC1
    k_conv_fused<8, 8, true><<<nbC, TB, 0, stream>>>(bufB, neigh, partC0, nbC, N3,
                                                     bn1_g, bn1_b, conv1_w, conv1_b,
                                                     bufA, partC1, N3);

    // 6) conv2: (N3,8) -> (N3,2) (bufA -> d_out), finalize partC1
    k_conv_fused<8, 2, false><<<nbC, TB, 0, stream>>>(bufA, neigh, partC1, nbC, N3,
                                                      bn2_g, bn2_b, conv2_w, conv2_b,
                                                      (float*)d_out, nullptr, N3);
}